// Round 1
// baseline (604.173 us; speedup 1.0000x reference)
//
#include <hip/hip_runtime.h>

typedef unsigned char u8;

#define TT 1024
#define BB 512
#define LL 50
#define STOPI 48
#define STARTI 49
#define NEGV -10000.0f

// ws layout:
//   [0, 2048)             : int idx[512]   (argmax of final vit per batch)
//   [4096, 4096+B*50*T)   : u8 ptr[B][50][T]  backpointers, TRANSPOSED [label][time]

// fwd: 4 waves per batch; the 50-wide 'from'-reduction is split across waves
// (13 candidates each, range padded to 52 with -1e5 sentinels that can never win).
// Per step: each wave scans its 13 candidates, partials (val,idx) are exchanged
// via LDS, and ALL waves combine in wave order (first-index tie semantics kept).
// Barriers are bare s_barrier with producer-side lgkmcnt(0) -- NO vmcnt drain, so
// backpointer stores and the feats prefetch stay in flight across every step.
__global__ __launch_bounds__(256) void viterbi_fwd(
    const float* __restrict__ feats, const int* __restrict__ lens,
    const float* __restrict__ trans, float* __restrict__ out_scores,
    int* __restrict__ idx_ws, u8* __restrict__ ptr_ws)
{
    const int b    = blockIdx.x;
    const int tid  = threadIdx.x;
    const int lane = tid & 63;
    const int w    = __builtin_amdgcn_readfirstlane(tid >> 6);  // wave id 0..3 (SGPR)
    const int off  = w * 13;                                    // from-range start
    const int row  = (lane < LL) ? lane : (LL - 1);             // 'to' label, clamped

    // this wave's 13 transition weights for 'to'=row: trans[row][off+jj]
    // pad (j>=50) = -1e5: with |scores| <= ~3e3 it can never win the max.
    float trrv[13];
#pragma unroll
    for (int jj = 0; jj < 13; ++jj) {
        const int j = off + jj;
        trrv[jj] = (j < LL) ? trans[row * LL + j] : -1.0e5f;
    }
    const float tr_stop = trans[STOPI * LL + row];
    const int len = lens[b];
    const int nchunks = (len + 15) >> 4;    // 16-step chunks with real work

    float vit = (lane == STARTI) ? 0.0f : NEGV;   // every wave keeps a full copy

    __shared__ float  featbuf[1024];          // one 16-step chunk (800 floats used)
    __shared__ float2 partial[2][4][64];      // [t&1][wave][lane] = (val, idx bits)

    const float* fb = feats + (size_t)b * (TT * LL);
    u8* pt = ptr_ws + (size_t)b * (TT * LL) + (size_t)row * TT;   // [to][t]

    // prefetch chunk 0: one float4 per thread (200 needed, clamp the rest)
    const int ld = (tid < 200) ? tid : 199;
    float4 nf = ((const float4*)fb)[ld];

    // 13-candidate scan as two sub-chains (7+6) to cut dep latency; strict '>'
    // with ascending j preserves the reference's first-index argmax.
#define SCAN13(BV, BI)                                                         \
    {                                                                          \
        float b0_ = -3.4e38f, b1_ = -3.4e38f;                                  \
        int   i0_ = off, i1_ = off + 7;                                        \
        _Pragma("unroll")                                                      \
        for (int jj = 0; jj < 7; ++jj) {                                       \
            const float s = __int_as_float(__builtin_amdgcn_readlane(          \
                                __float_as_int(vit), off + jj)) + trrv[jj];    \
            if (s > b0_) { b0_ = s; i0_ = off + jj; }                          \
        }                                                                      \
        _Pragma("unroll")                                                      \
        for (int jj = 7; jj < 13; ++jj) {                                      \
            const float s = __int_as_float(__builtin_amdgcn_readlane(          \
                                __float_as_int(vit), off + jj)) + trrv[jj];    \
            if (s > b1_) { b1_ = s; i1_ = off + jj; }                          \
        }                                                                      \
        if (b1_ > b0_) { b0_ = b1_; i0_ = i1_; }                               \
        (BV) = b0_; (BI) = i0_;                                                \
    }

// combine 4 wave-partials in wave order (ties keep the lower wave = lower j)
#define COMBINE(PAR, BV, BI)                                                   \
    {                                                                          \
        const float2 p0 = (PAR)[0][lane];                                      \
        const float2 p1 = (PAR)[1][lane];                                      \
        const float2 p2 = (PAR)[2][lane];                                      \
        const float2 p3 = (PAR)[3][lane];                                      \
        (BV) = p0.x; (BI) = __float_as_int(p0.y);                              \
        if (p1.x > (BV)) { (BV) = p1.x; (BI) = __float_as_int(p1.y); }         \
        if (p2.x > (BV)) { (BV) = p2.x; (BI) = __float_as_int(p2.y); }         \
        if (p3.x > (BV)) { (BV) = p3.x; (BI) = __float_as_int(p3.y); }         \
    }

    unsigned pk = 0;
    for (int c = 0; c < nchunks; ++c) {
        // stage chunk c regs->LDS (compiler inserts the vmcnt wait for nf here)
        if (tid < 200) ((float4*)featbuf)[tid] = nf;
        // prefetch chunk c+1 (waited ~16 steps from now, fully hidden)
        {
            const int cn = (c + 1 > 63) ? 63 : c + 1;
            nf = ((const float4*)(fb + cn * 800))[ld];
        }
        asm volatile("s_waitcnt lgkmcnt(0)" ::: "memory");
        __builtin_amdgcn_s_barrier();
        asm volatile("" ::: "memory");

#pragma unroll
        for (int i = 0; i < 16; ++i) {
            const int t = (c << 4) + i;
            // featbuf read BEFORE this step's barrier (keeps single-buffer legal
            // and hides DS latency under the scan)
            const float f = featbuf[i * 50 + lane];

            float bw; int iw;
            SCAN13(bw, iw)

            partial[t & 1][w][lane] = make_float2(bw, __int_as_float(iw));
            asm volatile("s_waitcnt lgkmcnt(0)" ::: "memory");
            __builtin_amdgcn_s_barrier();
            asm volatile("" ::: "memory");

            float bv; int bi;
            COMBINE(partial[t & 1], bv, bi)

            if (w == 0) {
                pk = (pk >> 8) | ((unsigned)bi << 24);    // byte (t&3) == idx at t
                if ((t & 3) == 3 && lane < LL)
                    *(unsigned*)(pt + t - 3) = pk;        // fire-and-forget
            }

            if (t < len) {                                // wave-uniform branch
                float nv = bv + f;
                if (t == len - 1) nv += tr_stop;
                vit = nv;
            }
        }
    }

    // frozen rows for t >= nchunks*16: one more cooperative scan of final vit,
    // then the constant backpointer pattern, fill distributed across waves.
    {
        float bw; int iw;
        SCAN13(bw, iw)
        partial[0][w][lane] = make_float2(bw, __int_as_float(iw));
        asm volatile("s_waitcnt lgkmcnt(0)" ::: "memory");
        __builtin_amdgcn_s_barrier();
        asm volatile("" ::: "memory");

        float bv; int bi;
        COMBINE(partial[0], bv, bi)

        const unsigned pat = (unsigned)bi * 0x01010101u;
        uint4 q; q.x = pat; q.y = pat; q.z = pat; q.w = pat;
        if (lane < LL)
            for (int c2 = nchunks + w; c2 < 64; c2 += 4)
                *(uint4*)(pt + (c2 << 4)) = q;
    }

    // final score / argmax over vit[0..49] (wave 0; single chain, first-index)
    if (w == 0) {
        float m = -3.4e38f; int mi = 0;
#pragma unroll
        for (int j = 0; j < LL; ++j) {
            float s = __int_as_float(__builtin_amdgcn_readlane(__float_as_int(vit), j));
            if (s > m) { m = s; mi = j; }
        }
        if (lane == 0) { out_scores[b] = m; idx_ws[b] = mi; }
    }
#undef SCAN13
#undef COMBINE
}

// Backtrack with chunked pointer-jumping: 32 chunks x 32 steps. (unchanged)
// ptr layout is transposed: lptr[label*1024 + t].
__global__ __launch_bounds__(64) void viterbi_bwd(
    const int* __restrict__ idx_ws, const u8* __restrict__ ptr_ws,
    float* __restrict__ out_paths)
{
    const int b = blockIdx.x;
    const int lane = threadIdx.x;

    __shared__ u8 lptr[TT * LL];    // 51200 B, [label][t]
    __shared__ u8 maps[32 * LL];    // maps[c*50 + entry] = exit state of chunk c
    __shared__ int entries[33];

    {
        const uint4* src = (const uint4*)(ptr_ws + (size_t)b * TT * LL);
        uint4* dst = (uint4*)lptr;
        for (int i = lane; i < (TT * LL) / 16; i += 64) dst[i] = src[i];
    }
    __syncthreads();

    // phase 1: all 1600 (chunk, entry) walks; 25 independent chains per lane
    {
        int st[25], tt[25], cidx[25];
#pragma unroll
        for (int k = 0; k < 25; ++k) {
            int w = k * 64 + lane;       // 0..1599
            int c = w / 50;
            int l = w - c * 50;
            st[k] = l;
            tt[k] = c * 32 + 31;
            cidx[k] = c * 50 + l;
        }
        for (int j = 0; j < 32; ++j) {
#pragma unroll
            for (int k = 0; k < 25; ++k) {
                st[k] = lptr[(st[k] << 10) + tt[k]];
                tt[k] -= 1;
            }
        }
#pragma unroll
        for (int k = 0; k < 25; ++k) maps[cidx[k]] = (u8)st[k];
    }
    __syncthreads();

    const int idx = idx_ws[b];

    // phase 2: compose chunk maps sequentially
    if (lane == 0) {
        int i = idx;
        for (int c = 31; c >= 0; --c) {
            entries[c + 1] = i;
            i = maps[c * 50 + i];
        }
        entries[0] = i;
    }
    __syncthreads();

    // phase 3: re-walk all 32 chunks in parallel, writing the path
    float* po = out_paths + (size_t)b * TT;
    if (lane < 32) {
        const int c = lane;
        int s = entries[c + 1];
        for (int j = 0; j < 32; ++j) {
            int t = c * 32 + 31 - j;
            int ni = lptr[(s << 10) + t];
            if (t > 0) po[t - 1] = (float)ni;   // paths[t-1] = back_seq[t]
            s = ni;
        }
    }
    if (lane == 0) po[TT - 1] = (float)idx;     // paths[T-1] = argmax(vit)
}

extern "C" void kernel_launch(void* const* d_in, const int* in_sizes, int n_in,
                              void* d_out, int out_size, void* d_ws, size_t ws_size,
                              hipStream_t stream) {
    const float* feats = (const float*)d_in[0];
    const int*   lens  = (const int*)d_in[1];
    const float* trans = (const float*)d_in[2];

    float* scores = (float*)d_out;          // [512]
    float* paths  = scores + BB;            // [512*1024] ints as floats

    int* idx_ws = (int*)d_ws;
    u8*  ptr_ws = (u8*)d_ws + 4096;

    viterbi_fwd<<<BB, 256, 0, stream>>>(feats, lens, trans, scores, idx_ws, ptr_ws);
    viterbi_bwd<<<BB, 64, 0, stream>>>(idx_ws, ptr_ws, paths);
}